// Round 8
// baseline (234.897 us; speedup 1.0000x reference)
//
#include <hip/hip_runtime.h>
#include <hip/hip_bf16.h>

#define T_LEN 1024
#define NH    16
#define CH    64
#define LSTR  64        // Q-prologue LDS row stride in shorts (128 B)

typedef __attribute__((ext_vector_type(8))) short short8;
typedef __attribute__((ext_vector_type(4))) float floatx4;
typedef unsigned long long u64;

__device__ __forceinline__ short f2bf(float x) {
    __hip_bfloat16 b = __float2bfloat16(x);   // RNE (prologue-only scalar path)
    return *(short*)&b;
}
// HW packed conversion: dst.lo16 = bf16(lo), dst.hi16 = bf16(hi).
__device__ __forceinline__ unsigned cvt_pk_bf16(float lo, float hi) {
    unsigned r;
    asm("v_cvt_pk_bf16_f32 %0, %1, %2" : "=v"(r) : "v"(lo), "v"(hi));
    return r;
}
// XOR block-swizzle for the Q prologue tile (stride-64-short rows).
__device__ __forceinline__ int fsw(int row) {
    return (((row & 7) ^ ((row >> 3) & 7)) << 3);
}
// K-row permutation (as r6/r7): physical s-row kperm(s) makes the swapped
// QK^T output land so the PV A-frag assembles in-register.
__device__ __forceinline__ int kperm(int s) {
    return (s & 0x23) | ((s & 0x18) >> 1) | ((s & 4) << 2);
}

// ---- mask bit-pack: (8,1024,1024) int32 -> (8,1024,16) u64 via wave ballot ----
__global__ __launch_bounds__(256)
void pack_mask_kernel(const int* __restrict__ mask, u64* __restrict__ pm)
{
    const int NW = 8 * T_LEN * (T_LEN / 64);   // 131072 words
    const int lane = threadIdx.x & 63;
    const int gw = (int)((blockIdx.x * blockDim.x + threadIdx.x) >> 6);
    const int nw = (int)((gridDim.x * blockDim.x) >> 6);
    for (int w0 = gw; w0 < NW; w0 += 4 * nw) {
        int v[4];
        #pragma unroll
        for (int i = 0; i < 4; ++i) {
            const int w = w0 + i * nw;
            v[i] = (w < NW) ? mask[(size_t)w * 64 + lane] : 0;
        }
        #pragma unroll
        for (int i = 0; i < 4; ++i) {
            const int w = w0 + i * nw;
            const u64 bb = __ballot(v[i] != 0);
            if (lane == 0 && w < NW) pm[w] = bb;
        }
    }
}

// One block = 8 waves = 512 threads: one (head-batch, 128-row Q tile).
// r7 + FRAGMENT-MAJOR K/V LDS: tiles stored as MFMA fragments
// (chunk = 64 lanes x 16B), so every fragment read is a wave-contiguous
// 1 KB ds_read_b128 at (base + lane*16 + imm) -> conflict-free, zero
// per-read address VALU. (r1/r3/r6/r7 all showed the identical 1.003e7
// conflict count: the old scattered fragment reads ran at ~2x min time —
// the LDS pipe was ~73% busy, half of it conflict overhead.)
// V staging: thread's global chunk (1 ch x 8 s) IS one fragment -> 1 b128
// write. K staging: transpose paid as 8 b16 writes at precomputed
// loop-invariant addresses. Everything else (swapped QK^T, kperm,
// P-in-register, packed mask, exp2, dbuf, 1 barrier/iter) = r7.
template<bool PM>
__global__ __launch_bounds__(512, 2)
void qkv_attn_kernel(const float* __restrict__ qkv,
                     const int* __restrict__ mask,
                     const u64* __restrict__ pm,
                     const float* __restrict__ qk_bias,
                     float* __restrict__ out)
{
    // 32 KB total. prologue: shorts 0..8191 = Q [128][LSTR] swizzled;
    // buffer B = shorts 8192..16383 (K|V fragment-major).
    // steady: A = shorts 0..8191, B = 8192..16383 (each: Kf 4 KBsh | Vf).
    // epilogue: whole 32 KB = Os fp32 [128][64] double-XOR swizzled.
    __shared__ __align__(16) char smem[32768];
    short* Qs = (short*)smem;
    short* KA = Qs;                      // shorts     0.. 4095 (8 KB)
    short* VA = Qs + 4096;               //         4096.. 8191
    short* KB = Qs + 8192;               //         8192..12287
    short* VB = Qs + 12288;              //        12288..16383
    float* Os = (float*)smem;

    const int tid  = threadIdx.x;
    const int wave = tid >> 6;
    const int lane = tid & 63;
    const int quad = lane >> 4;
    const int l16  = lane & 15;

    const int bh    = blockIdx.x;   // 0..127: consecutive bh -> XCD round-robin
    const int qtile = blockIdx.y;   // 0..7:  stride-128 ids keep a bh on ONE XCD
    const int b     = bh >> 4;
    const int h     = bh & 15;
    const int t0    = qtile * 128;

    const size_t qbase = ((size_t)b * (3 * NH * CH) + (size_t)h * (3 * CH)) * T_LEN;
    const float* kp = qkv + qbase + (size_t)CH * T_LEN;
    const float* vp = qkv + qbase + (size_t)(2 * CH) * T_LEN;

    const float b_l2e  = qk_bias[0] * 1.44269504088896f;  // exp(x)=exp2(x*log2e)
    const float qscale = 0.125f * 1.44269504088896f;      // folded into Q staging

    const int c64 = tid >> 3;          // 0..63 channel row
    const int sse = (tid & 7) * 8;     // 8-s segment per thread
    const int tse = (tid & 7) * 16;    // Q staging segment

    const float* kpr = kp + (size_t)c64 * T_LEN + sse;
    const float* vpr = vp + (size_t)c64 * T_LEN + sse;

    // fragment-read base (shorts): wave-contiguous 1 KB per (chunk) read
    const int fr = lane * 8;

    // ---- loop-invariant staging write addresses (fragment-major) ----
    // K frag (sub,h,q,l16) holds K[s: kperm^-1(sub*16+l16)][c = h*32+q*8+j].
    // Thread (c64, sse): channel c64, s in sse..sse+7 -> 8 scattered b16.
    const int hk = c64 >> 5, qk = (c64 >> 3) & 3, coff = c64 & 7;
    int kwadr[8];
    #pragma unroll
    for (int j = 0; j < 8; ++j) {
        const int sp = kperm(sse + j);
        kwadr[j] = (((sp >> 4) * 2 + hk) * 64 + qk * 16 + (sp & 15)) * 8 + coff;
    }
    // V frag (csub,h,q,l16) holds V[c = csub*16+l16][s = h*32+q*8+j]:
    // thread's chunk IS one fragment -> single b128 write.
    const int vwadr = (((c64 >> 4) * 2 + (sse >> 5)) * 64
                      + ((sse >> 3) & 3) * 16 + (c64 & 15)) * 8;

    const int tl = t0 + wave * 16 + l16;   // lane's own t (mask row)
    const u64* pmb = PM ? pm + ((size_t)(h & 7) * T_LEN + tl) * (T_LEN / 64) : nullptr;
    const int* mrow = mask + (size_t)(h & 7) * T_LEN * T_LEN + (size_t)tl * T_LEN;

    // ---- prefetch K/V tile 0 + mask word it=0 ----
    float4 kf0 = *(const float4*)(kpr);
    float4 kf1 = *(const float4*)(kpr + 4);
    float4 vf0 = *(const float4*)(vpr);
    float4 vf1 = *(const float4*)(vpr + 4);
    u64 mn = PM ? pmb[0] : 0ULL;

    // ---- stage Q transposed + swizzled + PRE-SCALED (shorts 0..8191) ----
    {
        const float* src = qkv + qbase + (size_t)c64 * T_LEN + t0 + tse;
        #pragma unroll
        for (int k = 0; k < 4; ++k) {
            float4 f = *(const float4*)(src + 4 * k);
            const int t = tse + 4 * k;
            Qs[(t + 0) * LSTR + (c64 ^ fsw(t + 0))] = f2bf(f.x * qscale);
            Qs[(t + 1) * LSTR + (c64 ^ fsw(t + 1))] = f2bf(f.y * qscale);
            Qs[(t + 2) * LSTR + (c64 ^ fsw(t + 2))] = f2bf(f.z * qscale);
            Qs[(t + 3) * LSTR + (c64 ^ fsw(t + 3))] = f2bf(f.w * qscale);
        }
    }
    __syncthreads();

    // ---- loop-invariant Q fragments (B-operand of swapped QK^T) ----
    const int qrow = wave * 16 + l16;
    const short8 aq0 = *(const short8*)&Qs[qrow * LSTR + ((quad * 8)      ^ fsw(qrow))];
    const short8 aq1 = *(const short8*)&Qs[qrow * LSTR + ((quad * 8 + 32) ^ fsw(qrow))];

    // ---- stage K/V tile 0 into buffer B (doesn't touch Q region) ----
    {
        const float kv[8] = {kf0.x,kf0.y,kf0.z,kf0.w,kf1.x,kf1.y,kf1.z,kf1.w};
        #pragma unroll
        for (int i2 = 0; i2 < 4; ++i2) {
            const unsigned w = cvt_pk_bf16(kv[2*i2], kv[2*i2+1]);
            KB[kwadr[2*i2]]   = (short)(w & 0xFFFFu);
            KB[kwadr[2*i2+1]] = (short)(w >> 16);
        }
        uint4 vw;
        vw.x = cvt_pk_bf16(vf0.x, vf0.y);
        vw.y = cvt_pk_bf16(vf0.z, vf0.w);
        vw.z = cvt_pk_bf16(vf1.x, vf1.y);
        vw.w = cvt_pk_bf16(vf1.z, vf1.w);
        *(uint4*)&VB[vwadr] = vw;
    }
    __syncthreads();

    const short one_bf = (short)0x3F80;
    const short8 ones8 = (short8){one_bf, one_bf, one_bf, one_bf,
                                  one_bf, one_bf, one_bf, one_bf};

    floatx4 o[4], ol;
    #pragma unroll
    for (int i = 0; i < 4; ++i) o[i] = (floatx4){0.f, 0.f, 0.f, 0.f};
    ol = (floatx4){0.f, 0.f, 0.f, 0.f};

    for (int it = 0; it < 16; ++it) {
        const int s0 = it * 64;
        // even it -> compute from B (tile0 staged there), stage next into A
        const short* Kc = (it & 1) ? KA : KB;
        const short* Vc = (it & 1) ? VA : VB;
        short* Kd = (it & 1) ? KB : KA;
        short* Vd = (it & 1) ? VB : VA;

        const u64 mcur = mn;
        // issue next-tile K/V global loads + mask word (hidden under compute)
        if (it < 15) {
            kf0 = *(const float4*)(kpr + s0 + 64);
            kf1 = *(const float4*)(kpr + s0 + 68);
            vf0 = *(const float4*)(vpr + s0 + 64);
            vf1 = *(const float4*)(vpr + s0 + 68);
            if (PM) mn = pmb[it + 1];
        }

        // ---- S^T = K Q (scale/bias pre-folded) -> P = exp2 masked, in-reg ----
        unsigned pa32[8];
        #pragma unroll
        for (int sub = 0; sub < 4; ++sub) {
            const short8 bk0 = *(const short8*)&Kc[(sub * 2 + 0) * 512 + fr];
            const short8 bk1 = *(const short8*)&Kc[(sub * 2 + 1) * 512 + fr];
            floatx4 acc = (floatx4){b_l2e, b_l2e, b_l2e, b_l2e};
            acc = __builtin_amdgcn_mfma_f32_16x16x32_bf16(bk0, aq0, acc, 0, 0, 0);
            acc = __builtin_amdgcn_mfma_f32_16x16x32_bf16(bk1, aq1, acc, 0, 0, 0);
            // original s for (sub, quad, r): 32*(sub>>1) + 8*quad + 4*(sub&1) + r
            const int sbase = 32 * (sub >> 1) + 4 * (sub & 1) + 8 * quad;
            unsigned mseg = 0;
            if (PM) mseg = (unsigned)(mcur >> sbase) & 0xFu;
            float f[4];
            #pragma unroll
            for (int r = 0; r < 4; ++r) {
                bool keep;
                if (PM) keep = ((mseg >> r) & 1u) != 0;
                else    keep = mrow[s0 + sbase + r] != 0;
                const float e = __builtin_amdgcn_exp2f(acc[r]);
                f[r] = keep ? e : 0.f;
            }
            pa32[sub * 2 + 0] = cvt_pk_bf16(f[0], f[1]);
            pa32[sub * 2 + 1] = cvt_pk_bf16(f[2], f[3]);
        }
        // PV A-frags directly from registers (kperm made the order line up)
        const short8 ap0 = *(const short8*)&pa32[0];   // s  0..31 slice
        const short8 ap1 = *(const short8*)&pa32[4];   // s 32..63 slice

        // ---- O += P V ; l += P . 1 ----
        __builtin_amdgcn_s_setprio(1);
        #pragma unroll
        for (int csub = 0; csub < 4; ++csub) {
            const short8 bv0 = *(const short8*)&Vc[(csub * 2 + 0) * 512 + fr];
            const short8 bv1 = *(const short8*)&Vc[(csub * 2 + 1) * 512 + fr];
            o[csub] = __builtin_amdgcn_mfma_f32_16x16x32_bf16(ap0, bv0, o[csub], 0, 0, 0);
            o[csub] = __builtin_amdgcn_mfma_f32_16x16x32_bf16(ap1, bv1, o[csub], 0, 0, 0);
        }
        ol = __builtin_amdgcn_mfma_f32_16x16x32_bf16(ap0, ones8, ol, 0, 0, 0);
        ol = __builtin_amdgcn_mfma_f32_16x16x32_bf16(ap1, ones8, ol, 0, 0, 0);
        __builtin_amdgcn_s_setprio(0);

        // ---- write prefetched next tile into the other buffer; one barrier ----
        if (it < 15) {
            const float kv[8] = {kf0.x,kf0.y,kf0.z,kf0.w,kf1.x,kf1.y,kf1.z,kf1.w};
            #pragma unroll
            for (int i2 = 0; i2 < 4; ++i2) {
                const unsigned w = cvt_pk_bf16(kv[2*i2], kv[2*i2+1]);
                Kd[kwadr[2*i2]]   = (short)(w & 0xFFFFu);
                Kd[kwadr[2*i2+1]] = (short)(w >> 16);
            }
            uint4 vw;
            vw.x = cvt_pk_bf16(vf0.x, vf0.y);
            vw.y = cvt_pk_bf16(vf0.z, vf0.w);
            vw.z = cvt_pk_bf16(vf1.x, vf1.y);
            vw.w = cvt_pk_bf16(vf1.z, vf1.w);
            *(uint4*)&Vd[vwadr] = vw;
            __syncthreads();
        }
    }

    // ---- epilogue: Os fp32 [128][64] fills the whole 32 KB; double-XOR
    //      swizzle (col ^ (wave<<3) ^ (quad<<4)) -> max 2-way on both sides ----
    __syncthreads();   // all compute done before Os overwrites K/V buffers
    float inv[4];
    #pragma unroll
    for (int r = 0; r < 4; ++r) inv[r] = (ol[r] > 0.f) ? 1.f / ol[r] : 0.f;
    const int okeyw = (wave << 3) ^ (quad << 4);
    #pragma unroll
    for (int csub = 0; csub < 4; ++csub)
        #pragma unroll
        for (int r = 0; r < 4; ++r)
            Os[(wave * 16 + quad * 4 + r) * 64 + ((csub * 16 + l16) ^ okeyw)] =
                o[csub][r] * inv[r];
    __syncthreads();
    {
        float* dst = out + ((size_t)b * (NH * CH) + (size_t)h * CH + c64) * T_LEN
                   + t0 + tse;
        #pragma unroll
        for (int k = 0; k < 4; ++k) {
            float4 f;
            #pragma unroll
            for (int j = 0; j < 4; ++j) {
                const int rl = tse + 4 * k + j;
                const int ok = ((rl >> 4) << 3) ^ (((rl >> 2) & 3) << 4);
                ((float*)&f)[j] = Os[rl * 64 + (c64 ^ ok)];
            }
            *(float4*)(dst + 4 * k) = f;
        }
    }
}

extern "C" void kernel_launch(void* const* d_in, const int* in_sizes, int n_in,
                              void* d_out, int out_size, void* d_ws, size_t ws_size,
                              hipStream_t stream) {
    const float* qkv     = (const float*)d_in[0];
    const int*   mask    = (const int*)d_in[1];
    const float* qk_bias = (const float*)d_in[2];
    float*       out     = (float*)d_out;

    const size_t pm_bytes = (size_t)8 * T_LEN * (T_LEN / 64) * sizeof(u64);  // 1 MiB
    u64* pm = nullptr;
    if (d_ws && ws_size >= pm_bytes) {
        pm = (u64*)d_ws;
        pack_mask_kernel<<<2048, 256, 0, stream>>>(mask, pm);
    }

    dim3 grid(8 * NH, T_LEN / 128);  // (head-batches, q-tiles) = (128, 8)
    if (pm) qkv_attn_kernel<true ><<<grid, 512, 0, stream>>>(qkv, mask, pm, qk_bias, out);
    else    qkv_attn_kernel<false><<<grid, 512, 0, stream>>>(qkv, mask, nullptr, qk_bias, out);
}

// Round 9
// 230.159 us; speedup vs baseline: 1.0206x; 1.0206x over previous
//
#include <hip/hip_runtime.h>
#include <hip/hip_bf16.h>

#define T_LEN 1024
#define NH    16
#define CH    64
#define LSTR  64        // Q-prologue LDS row stride in shorts (128 B)
#define FSTR  520       // fragment stride in shorts (512 + 8 pad: 1040 B; the
                        // pad puts frag-index back into the bank equation)
#define VOFF  (8 * FSTR)   // V-region offset within a buffer (shorts)

typedef __attribute__((ext_vector_type(8))) short short8;
typedef __attribute__((ext_vector_type(4))) float floatx4;
typedef unsigned long long u64;

__device__ __forceinline__ short f2bf(float x) {
    __hip_bfloat16 b = __float2bfloat16(x);   // RNE (prologue-only scalar path)
    return *(short*)&b;
}
// HW packed conversion: dst.lo16 = bf16(lo), dst.hi16 = bf16(hi).
__device__ __forceinline__ unsigned cvt_pk_bf16(float lo, float hi) {
    unsigned r;
    asm("v_cvt_pk_bf16_f32 %0, %1, %2" : "=v"(r) : "v"(lo), "v"(hi));
    return r;
}
// XOR block-swizzle for the Q prologue tile (stride-64-short rows).
__device__ __forceinline__ int fsw(int row) {
    return (((row & 7) ^ ((row >> 3) & 7)) << 3);
}
// K-row permutation (r6+): physical s-row kperm(s) makes the swapped
// QK^T output land so the PV A-frag assembles in-register.
__device__ __forceinline__ int kperm(int s) {
    return (s & 0x23) | ((s & 0x18) >> 1) | ((s & 4) << 2);
}
// Block-placement XOR-fold: logical 16B block bi of a fragment is stored at
// physical slot bi ^ ((bi>>3)&7).  With FSTR=520 this makes frag reads,
// V b128 writes conflict-free and K b16 writes worst-case 2-way (free).
__device__ __forceinline__ int bfold(int bi) {
    return bi ^ ((bi >> 3) & 7);
}

// ---- mask bit-pack: (8,1024,1024) int32 -> (8,1024,16) u64 via wave ballot ----
__global__ __launch_bounds__(256)
void pack_mask_kernel(const int* __restrict__ mask, u64* __restrict__ pm)
{
    const int NW = 8 * T_LEN * (T_LEN / 64);   // 131072 words
    const int lane = threadIdx.x & 63;
    const int gw = (int)((blockIdx.x * blockDim.x + threadIdx.x) >> 6);
    const int nw = (int)((gridDim.x * blockDim.x) >> 6);
    for (int w0 = gw; w0 < NW; w0 += 4 * nw) {
        int v[4];
        #pragma unroll
        for (int i = 0; i < 4; ++i) {
            const int w = w0 + i * nw;
            v[i] = (w < NW) ? mask[(size_t)w * 64 + lane] : 0;
        }
        #pragma unroll
        for (int i = 0; i < 4; ++i) {
            const int w = w0 + i * nw;
            const u64 bb = __ballot(v[i] != 0);
            if (lane == 0 && w < NW) pm[w] = bb;
        }
    }
}

// One block = 8 waves = 512 threads: one (head-batch, 128-row Q tile).
// r8 chassis (fragment-major K/V, swapped QK^T, kperm, P-in-register,
// packed mask, exp2, dbuf, 1 barrier/iter) + conflict-free LDS placement:
// FSTR=520 padding + bfold block permutation.  r8's measured 1.42e7
// conflict-cycles (~23 us) came from the staging writes (8-way on both K
// b16 scatter and V b128) — bank arithmetic with the pad+fold makes reads
// and V writes conflict-free and K writes 2-way (free).
template<bool PM>
__global__ __launch_bounds__(512, 2)
void qkv_attn_kernel(const float* __restrict__ qkv,
                     const int* __restrict__ mask,
                     const u64* __restrict__ pm,
                     const float* __restrict__ qk_bias,
                     float* __restrict__ out)
{
    // 33280 B. prologue: shorts 0..8191 = Q [128][LSTR] swizzled (inside A);
    // buffers: A = shorts 0..8319 (K) | 4160..8319 (V)?  Layout:
    //   KA = 0..4159, VA = 4160..8319, KB = 8320..12479, VB = 12480..16639.
    // tile 0 staged into B (doesn't touch Q). epilogue: Os fp32 32 KB.
    __shared__ __align__(16) char smem[4 * VOFF * 2];   // 33280 B
    short* Qs = (short*)smem;
    short* KA = Qs;                       // frags 0..7 (FSTR each)
    short* VA = Qs + VOFF;
    short* KB = Qs + 2 * VOFF;
    short* VB = Qs + 3 * VOFF;
    float* Os = (float*)smem;

    const int tid  = threadIdx.x;
    const int wave = tid >> 6;
    const int lane = tid & 63;
    const int quad = lane >> 4;
    const int l16  = lane & 15;

    const int bh    = blockIdx.x;   // 0..127: consecutive bh -> XCD round-robin
    const int qtile = blockIdx.y;   // 0..7:  stride-128 ids keep a bh on ONE XCD
    const int b     = bh >> 4;
    const int h     = bh & 15;
    const int t0    = qtile * 128;

    const size_t qbase = ((size_t)b * (3 * NH * CH) + (size_t)h * (3 * CH)) * T_LEN;
    const float* kp = qkv + qbase + (size_t)CH * T_LEN;
    const float* vp = qkv + qbase + (size_t)(2 * CH) * T_LEN;

    const float b_l2e  = qk_bias[0] * 1.44269504088896f;  // exp(x)=exp2(x*log2e)
    const float qscale = 0.125f * 1.44269504088896f;      // folded into Q staging

    const int c64 = tid >> 3;          // 0..63 channel row
    const int sse = (tid & 7) * 8;     // 8-s segment per thread
    const int tse = (tid & 7) * 16;    // Q staging segment

    const float* kpr = kp + (size_t)c64 * T_LEN + sse;
    const float* vpr = vp + (size_t)c64 * T_LEN + sse;

    // fragment-read base (shorts): folded block of this lane, 16B-aligned
    const int bsl8 = bfold(lane) * 8;

    // ---- loop-invariant staging write addresses (fragment-major, folded) ----
    // K frag fk=(sp>>4)*2+hk, block bi = qk*16 + (sp&15), element coff.
    const int hk = c64 >> 5, qk = (c64 >> 3) & 3, coff = c64 & 7;
    int kwadr[8];
    #pragma unroll
    for (int j = 0; j < 8; ++j) {
        const int sp = kperm(sse + j);
        const int fk = (sp >> 4) * 2 + hk;
        const int bi = qk * 16 + (sp & 15);
        kwadr[j] = fk * FSTR + bfold(bi) * 8 + coff;
    }
    // V frag fv=(c64>>4)*2+(sse>>5), block bi = ((sse>>3)&3)*16 + (c64&15):
    // thread's chunk IS one block -> single b128 write.
    const int vwadr = ((c64 >> 4) * 2 + (sse >> 5)) * FSTR
                    + bfold(((sse >> 3) & 3) * 16 + (c64 & 15)) * 8;

    const int tl = t0 + wave * 16 + l16;   // lane's own t (mask row)
    const u64* pmb = PM ? pm + ((size_t)(h & 7) * T_LEN + tl) * (T_LEN / 64) : nullptr;
    const int* mrow = mask + (size_t)(h & 7) * T_LEN * T_LEN + (size_t)tl * T_LEN;

    // ---- prefetch K/V tile 0 + mask word it=0 ----
    float4 kf0 = *(const float4*)(kpr);
    float4 kf1 = *(const float4*)(kpr + 4);
    float4 vf0 = *(const float4*)(vpr);
    float4 vf1 = *(const float4*)(vpr + 4);
    u64 mn = PM ? pmb[0] : 0ULL;

    // ---- stage Q transposed + swizzled + PRE-SCALED (shorts 0..8191) ----
    {
        const float* src = qkv + qbase + (size_t)c64 * T_LEN + t0 + tse;
        #pragma unroll
        for (int k = 0; k < 4; ++k) {
            float4 f = *(const float4*)(src + 4 * k);
            const int t = tse + 4 * k;
            Qs[(t + 0) * LSTR + (c64 ^ fsw(t + 0))] = f2bf(f.x * qscale);
            Qs[(t + 1) * LSTR + (c64 ^ fsw(t + 1))] = f2bf(f.y * qscale);
            Qs[(t + 2) * LSTR + (c64 ^ fsw(t + 2))] = f2bf(f.z * qscale);
            Qs[(t + 3) * LSTR + (c64 ^ fsw(t + 3))] = f2bf(f.w * qscale);
        }
    }
    __syncthreads();

    // ---- loop-invariant Q fragments (B-operand of swapped QK^T) ----
    const int qrow = wave * 16 + l16;
    const short8 aq0 = *(const short8*)&Qs[qrow * LSTR + ((quad * 8)      ^ fsw(qrow))];
    const short8 aq1 = *(const short8*)&Qs[qrow * LSTR + ((quad * 8 + 32) ^ fsw(qrow))];

    // ---- stage K/V tile 0 into buffer B (doesn't touch Q region) ----
    {
        const float kv[8] = {kf0.x,kf0.y,kf0.z,kf0.w,kf1.x,kf1.y,kf1.z,kf1.w};
        #pragma unroll
        for (int i2 = 0; i2 < 4; ++i2) {
            const unsigned w = cvt_pk_bf16(kv[2*i2], kv[2*i2+1]);
            KB[kwadr[2*i2]]   = (short)(w & 0xFFFFu);
            KB[kwadr[2*i2+1]] = (short)(w >> 16);
        }
        uint4 vw;
        vw.x = cvt_pk_bf16(vf0.x, vf0.y);
        vw.y = cvt_pk_bf16(vf0.z, vf0.w);
        vw.z = cvt_pk_bf16(vf1.x, vf1.y);
        vw.w = cvt_pk_bf16(vf1.z, vf1.w);
        *(uint4*)&VB[vwadr] = vw;
    }
    __syncthreads();

    const short one_bf = (short)0x3F80;
    const short8 ones8 = (short8){one_bf, one_bf, one_bf, one_bf,
                                  one_bf, one_bf, one_bf, one_bf};

    floatx4 o[4], ol;
    #pragma unroll
    for (int i = 0; i < 4; ++i) o[i] = (floatx4){0.f, 0.f, 0.f, 0.f};
    ol = (floatx4){0.f, 0.f, 0.f, 0.f};

    for (int it = 0; it < 16; ++it) {
        const int s0 = it * 64;
        // even it -> compute from B (tile0 staged there), stage next into A
        const short* Kc = (it & 1) ? KA : KB;
        const short* Vc = (it & 1) ? VA : VB;
        short* Kd = (it & 1) ? KB : KA;
        short* Vd = (it & 1) ? VB : VA;

        const u64 mcur = mn;
        // issue next-tile K/V global loads + mask word (hidden under compute)
        if (it < 15) {
            kf0 = *(const float4*)(kpr + s0 + 64);
            kf1 = *(const float4*)(kpr + s0 + 68);
            vf0 = *(const float4*)(vpr + s0 + 64);
            vf1 = *(const float4*)(vpr + s0 + 68);
            if (PM) mn = pmb[it + 1];
        }

        // ---- S^T = K Q (scale/bias pre-folded) -> P = exp2 masked, in-reg ----
        unsigned pa32[8];
        #pragma unroll
        for (int sub = 0; sub < 4; ++sub) {
            const short8 bk0 = *(const short8*)&Kc[(sub * 2 + 0) * FSTR + bsl8];
            const short8 bk1 = *(const short8*)&Kc[(sub * 2 + 1) * FSTR + bsl8];
            floatx4 acc = (floatx4){b_l2e, b_l2e, b_l2e, b_l2e};
            acc = __builtin_amdgcn_mfma_f32_16x16x32_bf16(bk0, aq0, acc, 0, 0, 0);
            acc = __builtin_amdgcn_mfma_f32_16x16x32_bf16(bk1, aq1, acc, 0, 0, 0);
            // original s for (sub, quad, r): 32*(sub>>1) + 8*quad + 4*(sub&1) + r
            const int sbase = 32 * (sub >> 1) + 4 * (sub & 1) + 8 * quad;
            unsigned mseg = 0;
            if (PM) mseg = (unsigned)(mcur >> sbase) & 0xFu;
            float f[4];
            #pragma unroll
            for (int r = 0; r < 4; ++r) {
                bool keep;
                if (PM) keep = ((mseg >> r) & 1u) != 0;
                else    keep = mrow[s0 + sbase + r] != 0;
                const float e = __builtin_amdgcn_exp2f(acc[r]);
                f[r] = keep ? e : 0.f;
            }
            pa32[sub * 2 + 0] = cvt_pk_bf16(f[0], f[1]);
            pa32[sub * 2 + 1] = cvt_pk_bf16(f[2], f[3]);
        }
        // PV A-frags directly from registers (kperm made the order line up)
        const short8 ap0 = *(const short8*)&pa32[0];   // s  0..31 slice
        const short8 ap1 = *(const short8*)&pa32[4];   // s 32..63 slice

        // ---- O += P V ; l += P . 1 ----
        __builtin_amdgcn_s_setprio(1);
        #pragma unroll
        for (int csub = 0; csub < 4; ++csub) {
            const short8 bv0 = *(const short8*)&Vc[(csub * 2 + 0) * FSTR + bsl8];
            const short8 bv1 = *(const short8*)&Vc[(csub * 2 + 1) * FSTR + bsl8];
            o[csub] = __builtin_amdgcn_mfma_f32_16x16x32_bf16(ap0, bv0, o[csub], 0, 0, 0);
            o[csub] = __builtin_amdgcn_mfma_f32_16x16x32_bf16(ap1, bv1, o[csub], 0, 0, 0);
        }
        ol = __builtin_amdgcn_mfma_f32_16x16x32_bf16(ap0, ones8, ol, 0, 0, 0);
        ol = __builtin_amdgcn_mfma_f32_16x16x32_bf16(ap1, ones8, ol, 0, 0, 0);
        __builtin_amdgcn_s_setprio(0);

        // ---- write prefetched next tile into the other buffer; one barrier ----
        if (it < 15) {
            const float kv[8] = {kf0.x,kf0.y,kf0.z,kf0.w,kf1.x,kf1.y,kf1.z,kf1.w};
            #pragma unroll
            for (int i2 = 0; i2 < 4; ++i2) {
                const unsigned w = cvt_pk_bf16(kv[2*i2], kv[2*i2+1]);
                Kd[kwadr[2*i2]]   = (short)(w & 0xFFFFu);
                Kd[kwadr[2*i2+1]] = (short)(w >> 16);
            }
            uint4 vw;
            vw.x = cvt_pk_bf16(vf0.x, vf0.y);
            vw.y = cvt_pk_bf16(vf0.z, vf0.w);
            vw.z = cvt_pk_bf16(vf1.x, vf1.y);
            vw.w = cvt_pk_bf16(vf1.z, vf1.w);
            *(uint4*)&Vd[vwadr] = vw;
            __syncthreads();
        }
    }

    // ---- epilogue: Os fp32 [128][64] (32 KB); double-XOR swizzle
    //      (col ^ (wave<<3) ^ (quad<<4)) -> max 2-way on both sides ----
    __syncthreads();   // all compute done before Os overwrites K/V buffers
    float inv[4];
    #pragma unroll
    for (int r = 0; r < 4; ++r) inv[r] = (ol[r] > 0.f) ? 1.f / ol[r] : 0.f;
    const int okeyw = (wave << 3) ^ (quad << 4);
    #pragma unroll
    for (int csub = 0; csub < 4; ++csub)
        #pragma unroll
        for (int r = 0; r < 4; ++r)
            Os[(wave * 16 + quad * 4 + r) * 64 + ((csub * 16 + l16) ^ okeyw)] =
                o[csub][r] * inv[r];
    __syncthreads();
    {
        float* dst = out + ((size_t)b * (NH * CH) + (size_t)h * CH + c64) * T_LEN
                   + t0 + tse;
        #pragma unroll
        for (int k = 0; k < 4; ++k) {
            float4 f;
            #pragma unroll
            for (int j = 0; j < 4; ++j) {
                const int rl = tse + 4 * k + j;
                const int ok = ((rl >> 4) << 3) ^ (((rl >> 2) & 3) << 4);
                ((float*)&f)[j] = Os[rl * 64 + (c64 ^ ok)];
            }
            *(float4*)(dst + 4 * k) = f;
        }
    }
}

extern "C" void kernel_launch(void* const* d_in, const int* in_sizes, int n_in,
                              void* d_out, int out_size, void* d_ws, size_t ws_size,
                              hipStream_t stream) {
    const float* qkv     = (const float*)d_in[0];
    const int*   mask    = (const int*)d_in[1];
    const float* qk_bias = (const float*)d_in[2];
    float*       out     = (float*)d_out;

    const size_t pm_bytes = (size_t)8 * T_LEN * (T_LEN / 64) * sizeof(u64);  // 1 MiB
    u64* pm = nullptr;
    if (d_ws && ws_size >= pm_bytes) {
        pm = (u64*)d_ws;
        pack_mask_kernel<<<2048, 256, 0, stream>>>(mask, pm);
    }

    dim3 grid(8 * NH, T_LEN / 128);  // (head-batches, q-tiles) = (128, 8)
    if (pm) qkv_attn_kernel<true ><<<grid, 512, 0, stream>>>(qkv, mask, pm, qk_bias, out);
    else    qkv_attn_kernel<false><<<grid, 512, 0, stream>>>(qkv, mask, nullptr, qk_bias, out);
}